// Round 15
// baseline (324.987 us; speedup 1.0000x reference)
//
#include <hip/hip_runtime.h>
#include <hip/hip_bf16.h>

// Problem constants (from reference)
#define S 2048
#define W 96
#define E 100
#define H 100
#define PD 50

typedef float f32x4 __attribute__((ext_vector_type(4)));

__device__ __forceinline__ float fast_rcp(float x) { return __builtin_amdgcn_rcpf(x); }

// Fused single-instruction DPP adds with EXPLICIT hazard mitigation.
// gfx9-lineage rule: DPP reading a VGPR written by the previous VALU op needs
// 2 wait states; the compiler's hazard recognizer can't see inside inline asm
// (R14 failed exactly here), so each stage carries its own s_nop 1. The last
// stage appends s_nop 3 so the following compiler-generated readlane is >=4
// states from our invisible DPP write.
#define DPP_SHR(X, IMM)                                                       \
    asm("s_nop 1\n\t"                                                         \
        "v_add_f32 %0, %0, %0 row_shr:" IMM                                   \
        " row_mask:0xf bank_mask:0xf bound_ctrl:0" : "+v"(X))
#define DPP_BC15(X)                                                           \
    asm("s_nop 1\n\t"                                                         \
        "v_add_f32 %0, %0, %0 row_bcast:15 row_mask:0xa bank_mask:0xf"        \
        : "+v"(X))
#define DPP_BC31_END(X)                                                       \
    asm("s_nop 1\n\t"                                                         \
        "v_add_f32 %0, %0, %0 row_bcast:31 row_mask:0xc bank_mask:0xf\n\t"    \
        "s_nop 3" : "+v"(X))

// K1: ragged-prefix mean pool over word embeddings + doc_feat accumulation
__global__ __launch_bounds__(128) void k_sent(const int* __restrict__ x,
                                              const float* __restrict__ word_emb,
                                              float* __restrict__ sent,
                                              float* __restrict__ doc_sum) {
    __shared__ int toks[W];
    __shared__ int s_len;
    const int i = blockIdx.x, t = threadIdx.x;
    if (t == 0) s_len = 0;
    __syncthreads();
    if (t < W) {
        int tok = x[i * W + t];
        toks[t] = tok;
        if (tok > 0) atomicAdd(&s_len, 1);
    }
    __syncthreads();
    const int len = s_len;
    if (t < E) {
        float acc = 0.0f;
        for (int j = 0; j < len; ++j)
            acc += word_emb[toks[j] * E + t];   // coalesced across t
        float val = acc / (float)max(len, 1);
        sent[i * E + t] = val;
        atomicAdd(&doc_sum[t], val * (1.0f / (float)S));
    }
}

// K2: doc = tanh(doc_feat @ fc1_w.T + fc1_b); cvec = Wc + Ws @ doc
__global__ __launch_bounds__(128) void k_doc(const float* __restrict__ doc_sum,
                                             const float* __restrict__ fc1_w,
                                             const float* __restrict__ fc1_b,
                                             const float* __restrict__ Wc,
                                             const float* __restrict__ Ws,
                                             float* __restrict__ cvec) {
    __shared__ float s_df[E];
    __shared__ float s_doc[H];
    const int t = threadIdx.x;
    if (t < E) s_df[t] = doc_sum[t];
    __syncthreads();
    if (t < H) {
        float acc = fc1_b[t];
        for (int k = 0; k < E; ++k) acc += s_df[k] * fc1_w[t * E + k];
        s_doc[t] = tanhf(acc);
    }
    __syncthreads();
    if (t < H) {
        float c = Wc[t];
        for (int j = 0; j < H; ++j) c += Ws[t * H + j] * s_doc[j];
        cvec[t] = c;
    }
}

// K3: per-row padded layout for the scan.
// packed row i = 64 float4 slots; slot m = (L2E*hWr[2m], h[2m], L2E*hWr[2m+1], h[2m+1]),
// zeros for k>=100.  Slot 50 .x (element 200, a DEAD hWr position) carries
// q[i] = -L2E*(h.cvec + pos.Wp + b). The scan sets lane 50's t0 = 1, so
// part(lane50) = t0*q contributes q to the wave sum with no extra fma.
__global__ __launch_bounds__(128) void k_row(const float* __restrict__ sent,
                                             const float* __restrict__ fc2_w,
                                             const float* __restrict__ fc2_b,
                                             const float* __restrict__ Wr,
                                             const float* __restrict__ cvec,
                                             const float* __restrict__ pos_emb,
                                             const float* __restrict__ Wp,
                                             const float* __restrict__ bptr,
                                             float* __restrict__ packed) {
    __shared__ float s_sent[E];
    __shared__ float s_h[H];
    __shared__ float red[128];
    const int i = blockIdx.x, t = threadIdx.x;
    float* row = packed + (size_t)i * 256;
    if (t < E) s_sent[t] = sent[i * E + t];
    __syncthreads();
    float hv = 0.0f;
    if (t < H) {
        float acc = fc2_b[t];
        for (int k = 0; k < E; ++k) acc += s_sent[k] * fc2_w[t * E + k];
        hv = tanhf(acc);
        s_h[t] = hv;
    }
    __syncthreads();
    {
        const int m = t >> 1, o = (t & 1) * 2;
        if (t < H) {
            float acc = 0.0f;
            for (int k = 0; k < H; ++k) acc += s_h[k] * Wr[k * H + t];   // coalesced across t
            row[m * 4 + o]     = 1.44269504f * acc;  // L2E * hWr
            row[m * 4 + o + 1] = hv;                 // h
        } else {
            if (t != 100) row[m * 4 + o] = 0.0f;   // dead w (element 200 reserved for q)
            row[m * 4 + o + 1] = 0.0f;             // dead h
        }
    }
    float p = 0.0f;
    if (t < H) p = hv * cvec[t];
    if (t < PD) p += pos_emb[i * PD + t] * Wp[t];
    red[t] = p;
    __syncthreads();
    for (int m = 64; m > 0; m >>= 1) {
        if (t < m) red[t] += red[t + m];
        __syncthreads();
    }
    if (t == 0) row[200] = -1.44269504f * (red[0] + bptr[0]);  // slot 50 .x
}

// K4: sequential scan, batch-8 double-buffered manual pipeline (R9 structure),
// pinned schedule. Chain: part-fma -> 6 fused+nop'd dpp-adds -> readlane ->
// exp2 -> depth-3 fma algebra -> rcp -> mul. Off-chain precomputes (t+h,
// 1+t*h, h^3/3, t*h^3/3) run parallel with the reduction. probbuf stores
// a = 1+2^total; prob = rcp(a) happens once per 64 steps at write time.
__global__ __launch_bounds__(64, 1) void k_scan(const f32x4* __restrict__ packed,
                                                float* __restrict__ out) {
    const int l = threadIdx.x;
    const f32x4* pf = packed + l;

    float t0 = (l == 50) ? 1.0f : 0.0f;   // t = tanh(s); lane50 carries q
    float t1 = 0.0f, probbuf = 1.0f;

    f32x4 x0, x1, x2, x3, x4, x5, x6, x7;
    f32x4 y0, y1, y2, y3, y4, y5, y6, y7;

#define SB() __builtin_amdgcn_sched_barrier(0)
#define ISSUE(AR, PTR) \
    asm volatile("global_load_dwordx4 %0, %1, off" : "=v"(AR) : "v"(PTR))
#define ISSUE8(P0, P1, P2, P3, P4, P5, P6, P7)                                \
    SB();                                                                     \
    ISSUE(P0, pf + 0 * 64); ISSUE(P1, pf + 1 * 64);                           \
    ISSUE(P2, pf + 2 * 64); ISSUE(P3, pf + 3 * 64);                           \
    ISSUE(P4, pf + 4 * 64); ISSUE(P5, pf + 5 * 64);                           \
    ISSUE(P6, pf + 6 * 64); ISSUE(P7, pf + 7 * 64);                           \
    pf += 8 * 64;                                                             \
    SB();
#define WAIT_ALL()                                                            \
    SB();                                                                     \
    asm volatile("s_waitcnt vmcnt(0)" ::: "memory");                          \
    SB();

#define STEP(CA_, IDX, G)                                                     \
    {                                                                         \
        const float w0 = CA_.x, h0 = CA_.y, w1 = CA_.z, h1 = CA_.w;           \
        /* off-chain precomputes: depend only on prev t and loaded data */    \
        float h30  = h0 * h0 * h0 * 0.33333334f;                              \
        float h31  = h1 * h1 * h1 * 0.33333334f;                              \
        float tph0 = t0 + h0, tph1 = t1 + h1;                                 \
        float c0   = fmaf(t0, h0, 1.0f), c1 = fmaf(t1, h1, 1.0f);             \
        float th30 = t0 * h30, th31 = t1 * h31;                               \
        float part = fmaf(t0, w0, t1 * w1);                                   \
        DPP_SHR(part, "1"); DPP_SHR(part, "2");                               \
        DPP_SHR(part, "4"); DPP_SHR(part, "8");                               \
        DPP_BC15(part); DPP_BC31_END(part);                                   \
        float total = __int_as_float(                                         \
            __builtin_amdgcn_readlane(__float_as_int(part), 63));             \
        float e2 = exp2f(total);     /* total = L2E*(hWr.tanh(s) - pre) */    \
        float av = e2 + 1.0f;        /* a; prob = 1/a (deferred to write) */  \
        float a2 = av * av;                                                   \
        float nA0 = fmaf(t0, e2, tph0), dA0 = e2 + c0;                        \
        float nA1 = fmaf(t1, e2, tph1), dA1 = e2 + c1;                        \
        float N0 = fmaf(a2, nA0, -h30), D0 = fmaf(a2, dA0, -th30);            \
        float N1 = fmaf(a2, nA1, -h31), D1 = fmaf(a2, dA1, -th31);            \
        t0 = N0 * fast_rcp(D0);                                               \
        t1 = N1 * fast_rcp(D1);                                               \
        probbuf = (l == ((G + IDX) & 63)) ? av : probbuf;                     \
    }
#define COMPUTE8(P0, P1, P2, P3, P4, P5, P6, P7, G)                           \
    STEP(P0, 0, G) STEP(P1, 1, G) STEP(P2, 2, G) STEP(P3, 3, G)               \
    STEP(P4, 4, G) STEP(P5, 5, G) STEP(P6, 6, G) STEP(P7, 7, G)               \
    if (((G) & 63) == 56) out[((G) & ~63) + l] = fast_rcp(probbuf);

    // Preload batch 0 into X and land it.
    ISSUE8(x0, x1, x2, x3, x4, x5, x6, x7)
    WAIT_ALL()

    for (int base = 0; base < S; base += 16) {
        ISSUE8(y0, y1, y2, y3, y4, y5, y6, y7)            // rows base+8..base+15
        COMPUTE8(x0, x1, x2, x3, x4, x5, x6, x7, base)    // rows base..base+7
        WAIT_ALL()                                        // Y landed (issued ~1500cy ago)
        ISSUE8(x0, x1, x2, x3, x4, x5, x6, x7)            // rows base+16..base+23
        COMPUTE8(y0, y1, y2, y3, y4, y5, y6, y7, base + 8)
        WAIT_ALL()                                        // X landed
    }
#undef COMPUTE8
#undef STEP
#undef WAIT_ALL
#undef ISSUE8
#undef ISSUE
#undef SB
}

extern "C" void kernel_launch(void* const* d_in, const int* in_sizes, int n_in,
                              void* d_out, int out_size, void* d_ws, size_t ws_size,
                              hipStream_t stream) {
    const int*   x        = (const int*)  d_in[0];
    const float* word_emb = (const float*)d_in[1];
    const float* pos_emb  = (const float*)d_in[2];
    const float* fc1_w    = (const float*)d_in[3];
    const float* fc1_b    = (const float*)d_in[4];
    const float* fc2_w    = (const float*)d_in[5];
    const float* fc2_b    = (const float*)d_in[6];
    const float* Wc       = (const float*)d_in[7];
    const float* Ws       = (const float*)d_in[8];
    const float* Wr       = (const float*)d_in[9];
    const float* Wp       = (const float*)d_in[10];
    const float* bptr     = (const float*)d_in[11];
    float* out = (float*)d_out;

    float* wsf      = (float*)d_ws;
    float* doc_sum  = wsf;                 // 128 (zeroed each call)
    float* cvec     = wsf + 128;           // 128
    float* sent     = wsf + 256;           // S*E = 204800
    float* packed   = sent + S * E;        // (S+16)*256 floats, 16B-aligned offset

    hipMemsetAsync(doc_sum, 0, E * sizeof(float), stream);
    hipMemsetAsync(packed + (size_t)S * 256, 0, 16 * 256 * sizeof(float), stream);
    k_sent<<<S, 128, 0, stream>>>(x, word_emb, sent, doc_sum);
    k_doc<<<1, 128, 0, stream>>>(doc_sum, fc1_w, fc1_b, Wc, Ws, cvec);
    k_row<<<S, 128, 0, stream>>>(sent, fc2_w, fc2_b, Wr, cvec, pos_emb, Wp, bptr, packed);
    k_scan<<<1, 64, 0, stream>>>((const f32x4*)packed, out);
}